// Round 4
// baseline (122.780 us; speedup 1.0000x reference)
//
#include <hip/hip_runtime.h>
#include <hip/hip_fp16.h>

// feature_grid: (512, 512, 4) float32
// location:     (N, 2) float32, N = 8388608
// out:          (N, 4) float32
//
// Strategy: precompute a "quad grid" in workspace: for each (x0,y0),
// all 4 bilinear corners packed fp16 into one 32B-aligned chunk ->
// the whole 2x2 neighborhood is in ONE 64B cache line. Per point:
// two 16B loads to the same line (2nd is an L1 hit) instead of two
// divergent line-misses 1024B apart.
#define GRID_H 512
#define GRID_W 512
#define NCELLS (GRID_H * GRID_W)

typedef float f32x4 __attribute__((ext_vector_type(4)));

struct alignas(16) Half8 { __half2 h[4]; };   // 16 bytes

// ---------------- build quad grid: 512x512 quads x 32 B = 8 MB ----------------
__global__ __launch_bounds__(256) void build_quad_kernel(
    const float4* __restrict__ g,    // [512*512] fp32 cells
    char* __restrict__ q)            // [512*512 * 32] bytes
{
    int i = blockIdx.x * blockDim.x + threadIdx.x;   // one thread per quad
    if (i >= NCELLS) return;
    int x = i >> 9;
    int y = i & (GRID_W - 1);
    if (x > GRID_H - 2) x = GRID_H - 2;   // clamp: duplicate edge quads (never sampled wrong)
    if (y > GRID_W - 2) y = GRID_W - 2;

    float4 c00 = g[x * GRID_W + y];
    float4 c01 = g[x * GRID_W + y + 1];
    float4 c10 = g[(x + 1) * GRID_W + y];
    float4 c11 = g[(x + 1) * GRID_W + y + 1];

    Half8 q0, q1;
    q0.h[0] = __floats2half2_rn(c00.x, c00.y);
    q0.h[1] = __floats2half2_rn(c00.z, c00.w);
    q0.h[2] = __floats2half2_rn(c01.x, c01.y);
    q0.h[3] = __floats2half2_rn(c01.z, c01.w);
    q1.h[0] = __floats2half2_rn(c10.x, c10.y);
    q1.h[1] = __floats2half2_rn(c10.z, c10.w);
    q1.h[2] = __floats2half2_rn(c11.x, c11.y);
    q1.h[3] = __floats2half2_rn(c11.z, c11.w);

    *reinterpret_cast<Half8*>(q + (size_t)i * 32)      = q0;
    *reinterpret_cast<Half8*>(q + (size_t)i * 32 + 16) = q1;
}

__device__ __forceinline__ f32x4 sample_quad(const char* __restrict__ q, float x, float y)
{
    float fx0 = fminf(fmaxf(floorf(x), 0.0f), (float)(GRID_H - 2));
    float fy0 = fminf(fmaxf(floorf(y), 0.0f), (float)(GRID_W - 2));
    int x0 = (int)fx0;
    int y0 = (int)fy0;
    float fx = x - fx0;
    float fy = y - fy0;

    size_t off = ((size_t)(x0 << 9 | y0)) * 32;
    Half8 r0 = *reinterpret_cast<const Half8*>(q + off);        // c00, c01
    Half8 r1 = *reinterpret_cast<const Half8*>(q + off + 16);   // c10, c11  (same 64B line)

    float2 a0 = __half22float2(r0.h[0]);  // f00 feat 0,1
    float2 a1 = __half22float2(r0.h[1]);  // f00 feat 2,3
    float2 b0 = __half22float2(r0.h[2]);  // f01 feat 0,1
    float2 b1 = __half22float2(r0.h[3]);  // f01 feat 2,3
    float2 c0 = __half22float2(r1.h[0]);  // f10 feat 0,1
    float2 c1 = __half22float2(r1.h[1]);  // f10 feat 2,3
    float2 d0 = __half22float2(r1.h[2]);  // f11 feat 0,1
    float2 d1 = __half22float2(r1.h[3]);  // f11 feat 2,3

    float gx = 1.0f - fx;
    float gy = 1.0f - fy;
    float w00 = gx * gy;
    float w01 = gx * fy;
    float w10 = fx * gy;
    float w11 = fx * fy;

    f32x4 r;
    r.x = a0.x * w00 + b0.x * w01 + c0.x * w10 + d0.x * w11;
    r.y = a0.y * w00 + b0.y * w01 + c0.y * w10 + d0.y * w11;
    r.z = a1.x * w00 + b1.x * w01 + c1.x * w10 + d1.x * w11;
    r.w = a1.y * w00 + b1.y * w01 + c1.y * w10 + d1.y * w11;
    return r;
}

__global__ __launch_bounds__(256) void bilinear_quad_kernel(
    const char* __restrict__ q,         // quad grid, 8 MB
    const f32x4* __restrict__ loc2,     // [npair] two points per element
    f32x4* __restrict__ out,            // [n] float4 outputs
    int npair, int n)
{
    const int stride = gridDim.x * blockDim.x;
    for (int i = blockIdx.x * blockDim.x + threadIdx.x; i < npair; i += stride) {
        f32x4 p = __builtin_nontemporal_load(&loc2[i]);
        f32x4 rA = sample_quad(q, p.x, p.y);
        f32x4 rB = sample_quad(q, p.z, p.w);
        __builtin_nontemporal_store(rA, &out[2 * i]);
        __builtin_nontemporal_store(rB, &out[2 * i + 1]);
    }
    if ((n & 1) && blockIdx.x == 0 && threadIdx.x == 0) {
        const float2* locs = (const float2*)loc2;
        float2 p = locs[n - 1];
        f32x4 r = sample_quad(q, p.x, p.y);
        out[n - 1] = r;
    }
}

// ---------------- fallback: fp16 row-pair grid (2 MB ws), R3's kernel ----------------
__global__ __launch_bounds__(256) void convert_grid_kernel(
    const float4* __restrict__ g, uint2* __restrict__ gh, int ncells)
{
    int i = blockIdx.x * blockDim.x + threadIdx.x;
    if (i < ncells) {
        float4 v = g[i];
        __half2 lo = __floats2half2_rn(v.x, v.y);
        __half2 hi = __floats2half2_rn(v.z, v.w);
        uint2 o;
        o.x = *reinterpret_cast<const unsigned int*>(&lo);
        o.y = *reinterpret_cast<const unsigned int*>(&hi);
        gh[i] = o;
    }
}

__device__ __forceinline__ f32x4 sample_rowpair(const char* __restrict__ gh, float x, float y)
{
    float fx0 = fminf(fmaxf(floorf(x), 0.0f), (float)(GRID_H - 2));
    float fy0 = fminf(fmaxf(floorf(y), 0.0f), (float)(GRID_W - 2));
    int x0 = (int)fx0, y0 = (int)fy0;
    float fx = x - fx0, fy = y - fy0;
    int c0 = x0 * GRID_W + y0;
    Half8 r0 = *reinterpret_cast<const Half8*>(gh + (size_t)c0 * 8);
    Half8 r1 = *reinterpret_cast<const Half8*>(gh + (size_t)(c0 + GRID_W) * 8);
    float2 a0 = __half22float2(r0.h[0]);
    float2 a1 = __half22float2(r0.h[1]);
    float2 b0 = __half22float2(r0.h[2]);
    float2 b1 = __half22float2(r0.h[3]);
    float2 c0f = __half22float2(r1.h[0]);
    float2 c1f = __half22float2(r1.h[1]);
    float2 d0 = __half22float2(r1.h[2]);
    float2 d1 = __half22float2(r1.h[3]);
    float gx = 1.0f - fx, gy = 1.0f - fy;
    float w00 = gx * gy, w01 = gx * fy, w10 = fx * gy, w11 = fx * fy;
    f32x4 r;
    r.x = a0.x * w00 + b0.x * w01 + c0f.x * w10 + d0.x * w11;
    r.y = a0.y * w00 + b0.y * w01 + c0f.y * w10 + d0.y * w11;
    r.z = a1.x * w00 + b1.x * w01 + c1f.x * w10 + d1.x * w11;
    r.w = a1.y * w00 + b1.y * w01 + c1f.y * w10 + d1.y * w11;
    return r;
}

__global__ __launch_bounds__(256) void bilinear_half_kernel(
    const char* __restrict__ gh, const f32x4* __restrict__ loc2,
    f32x4* __restrict__ out, int npair, int n)
{
    const int stride = gridDim.x * blockDim.x;
    for (int i = blockIdx.x * blockDim.x + threadIdx.x; i < npair; i += stride) {
        f32x4 p = __builtin_nontemporal_load(&loc2[i]);
        f32x4 rA = sample_rowpair(gh, p.x, p.y);
        f32x4 rB = sample_rowpair(gh, p.z, p.w);
        __builtin_nontemporal_store(rA, &out[2 * i]);
        __builtin_nontemporal_store(rB, &out[2 * i + 1]);
    }
    if ((n & 1) && blockIdx.x == 0 && threadIdx.x == 0) {
        const float2* locs = (const float2*)loc2;
        float2 p = locs[n - 1];
        f32x4 r = sample_rowpair(gh, p.x, p.y);
        out[n - 1] = r;
    }
}

extern "C" void kernel_launch(void* const* d_in, const int* in_sizes, int n_in,
                              void* d_out, int out_size, void* d_ws, size_t ws_size,
                              hipStream_t stream) {
    const float* grid_f32 = (const float*)d_in[0];
    const float* loc_f32  = (const float*)d_in[1];

    int n = in_sizes[1] / 2;
    int npair = n / 2;
    const size_t quad_bytes = (size_t)NCELLS * 32;   // 8 MB
    const size_t gh_bytes   = (size_t)NCELLS * 8;    // 2 MB

    const int block = 256;
    int blocks = (npair + block - 1) / block;
    if (blocks > 8192) blocks = 8192;
    if (blocks < 1) blocks = 1;

    if (ws_size >= quad_bytes) {
        build_quad_kernel<<<(NCELLS + 255) / 256, 256, 0, stream>>>(
            (const float4*)grid_f32, (char*)d_ws);
        bilinear_quad_kernel<<<blocks, block, 0, stream>>>(
            (const char*)d_ws, (const f32x4*)loc_f32, (f32x4*)d_out, npair, n);
    } else if (ws_size >= gh_bytes) {
        convert_grid_kernel<<<(NCELLS + 255) / 256, 256, 0, stream>>>(
            (const float4*)grid_f32, (uint2*)d_ws, NCELLS);
        bilinear_half_kernel<<<blocks, block, 0, stream>>>(
            (const char*)d_ws, (const f32x4*)loc_f32, (f32x4*)d_out, npair, n);
    }
}